// Round 11
// baseline (71.616 us; speedup 1.0000x reference)
//
#include <hip/hip_runtime.h>
#include <math.h>

#define S_LEN 2048
#define B_SZ  2
#define H_DIM 512
#define WIN   128
#define PAD   64
#define SP    (S_LEN + WIN)   /* 2176 padded seq length */
#define SCALE 0.044194173824159216f  /* 1/sqrt(512) */
#define TQ    32

typedef __bf16 bf16;
typedef __attribute__((ext_vector_type(8))) __bf16 bf16x8;
typedef __attribute__((ext_vector_type(4))) __bf16 bf16x4;
typedef __attribute__((ext_vector_type(4))) float f32x4;

#define GLDS16(g, l) __builtin_amdgcn_global_load_lds( \
    (const __attribute__((address_space(1))) void*)(g), \
    (__attribute__((address_space(3))) void*)(l), 16, 0, 0)

// ---------------- fused prep: x->bf16 | W->bf16 | pads | rope tables ----
__global__ __launch_bounds__(256) void prep_k(
    const float* __restrict__ x,
    const float* __restrict__ Wq, const float* __restrict__ Wk,
    const float* __restrict__ Wv, const float* __restrict__ Wo,
    bf16* __restrict__ xb, bf16* __restrict__ wb,
    bf16* __restrict__ pKb, bf16* __restrict__ pVT,
    float* __restrict__ sinT, float* __restrict__ cosT)
{
  int i = blockIdx.x * 256 + threadIdx.x;
  if (i < 262144) {                     // R0: x -> bf16
    int e = i * 8;
    float4 v0 = *(const float4*)(x + e);
    float4 v1 = *(const float4*)(x + e + 4);
    bf16x8 o = {(bf16)v0.x, (bf16)v0.y, (bf16)v0.z, (bf16)v0.w,
                (bf16)v1.x, (bf16)v1.y, (bf16)v1.z, (bf16)v1.w};
    *(bf16x8*)(xb + e) = o;
  } else if (i < 524288) {              // R1: weights -> bf16 (1-pass)
    int idx = (i - 262144) * 4;
    int m = idx >> 18;
    const float* src = (m == 0) ? Wq : (m == 1) ? Wk : (m == 2) ? Wv : Wo;
    float4 v = *(const float4*)(src + (idx & 262143));
    bf16x4 hv = {(bf16)v.x, (bf16)v.y, (bf16)v.z, (bf16)v.w};
    *(bf16x4*)(wb + idx) = hv;
  } else if (i < 557056) {              // R2: pads
    int idx = i - 524288;
    float4 z = {0.f, 0.f, 0.f, 0.f};
    if (idx < 16384) {        // pKb: 2b x 128 pad-rows x 512 cols
      int b = idx >> 13, r = (idx & 8191) >> 6, c = idx & 63;
      int row = (r < 64) ? r : (S_LEN + r);
      *(float4*)(pKb + ((size_t)b * SP + row) * 512 + c * 8) = z;
    } else {                  // pVT: 2b x 512 rows x 128 pad-cols
      int j = idx - 16384;
      int b = j >> 13, h = (j & 8191) >> 4, v = j & 15;
      int col = (v < 8) ? v * 8 : (S_LEN + PAD + (v - 8) * 8);
      *(float4*)(pVT + ((size_t)b * 512 + h) * SP + col) = z;
    }
  } else {                              // R3: rope tables
    int idx = i - 557056;               // [0, 262144) = s*128 + jj
    int s = idx >> 7, jj = idx & 127;
    float fqA = exp2f(-(float)jj * 0.10381025296523f);          // i = 2jj
    float fqB = exp2f(-(float)(2 * jj + 1) * 0.05190512648262f); // i = 2jj+1
    float aA = (float)s * fqA;
    float aB = (float)s * fqB;
    sinT[s * 256 + jj]       = sinf(aA);
    sinT[s * 256 + jj + 128] = cosf(aA);
    cosT[s * 256 + jj]       = sinf(aB);
    cosT[s * 256 + jj + 128] = cosf(aB);
  }
}

// ---------------- 1-pass bf16 MFMA GEMM, BK=64 (round-10 verified) ------
template<int MFR, int MODE>
__global__ __launch_bounds__(256) void gemm_k(
    const bf16* __restrict__ Ab, const bf16* __restrict__ Wb,
    const float* __restrict__ bq, const float* __restrict__ bk,
    const float* __restrict__ bv,
    const float* __restrict__ sinT, const float* __restrict__ cosT,
    bf16* __restrict__ oQ, bf16* __restrict__ oK, bf16* __restrict__ oVT,
    float* __restrict__ oOut)
{
  constexpr int BM = MFR * 32;
  constexpr int ABYTES = BM * 128;
  constexpr int BUFB = ABYTES + 128 * 128;
  __shared__ __align__(16) unsigned char smem[2 * BUFB];
  const int tid = threadIdx.x;
  const int lane = tid & 63, wid = tid >> 6;
  const int wm = wid >> 1, wn = wid & 1;
  const int row0 = blockIdx.x * BM;
  const int wrow0 = (MODE == 0 ? 0 : 1536) + blockIdx.y * 128;
  const int lr = lane & 15, lk = lane >> 4;

  f32x4 acc[MFR][4] = {};

  auto stage = [&](int k0, int bufsel) {
    unsigned char* buf = smem + bufsel * BUFB;
#pragma unroll
    for (int i = 0; i < MFR; i++) {         // A: BM rows x 8 slots of 16B
      int c = tid + i * 256;
      int r = c >> 3, p = c & 7, l = p ^ (r & 7);
      GLDS16(Ab + (size_t)(row0 + r) * 512 + k0 + l * 8, buf + c * 16);
    }
#pragma unroll
    for (int j = 0; j < 4; j++) {           // B: 128 rows x 8 slots of 16B
      int c = tid + j * 256;
      int r = c >> 3, p = c & 7, l = p ^ (r & 7);
      GLDS16(Wb + (size_t)(wrow0 + r) * 512 + k0 + l * 8, buf + ABYTES + c * 16);
    }
  };

  stage(0, 0);
  __syncthreads();
  for (int t = 0; t < 8; t++) {
    if (t < 7) stage((t + 1) * 64, (t + 1) & 1);
    const unsigned char* buf = smem + (t & 1) * BUFB;
    bf16x8 bfr[4][2];
#pragma unroll
    for (int ni = 0; ni < 4; ni++) {
      int r = wn * 64 + ni * 16 + lr;
      const unsigned char* base = buf + ABYTES + r * 128;
      int sw = (r & 7) << 4;
      bfr[ni][0] = *(const bf16x8*)(base + ((lk * 16) ^ sw));
      bfr[ni][1] = *(const bf16x8*)(base + ((64 + lk * 16) ^ sw));
    }
#pragma unroll
    for (int mi = 0; mi < MFR; mi++) {
      int r = wm * (MFR * 16) + mi * 16 + lr;
      const unsigned char* base = buf + r * 128;
      int sw = (r & 7) << 4;
      bf16x8 a0 = *(const bf16x8*)(base + ((lk * 16) ^ sw));
      bf16x8 a1 = *(const bf16x8*)(base + ((64 + lk * 16) ^ sw));
#pragma unroll
      for (int ni = 0; ni < 4; ni++) {
        acc[mi][ni] = __builtin_amdgcn_mfma_f32_16x16x32_bf16(a0, bfr[ni][0], acc[mi][ni], 0, 0, 0);
        acc[mi][ni] = __builtin_amdgcn_mfma_f32_16x16x32_bf16(a1, bfr[ni][1], acc[mi][ni], 0, 0, 0);
      }
    }
    __syncthreads();
  }

  const int rowb = row0 + wm * (MFR * 16) + ((lane >> 4) * 4);
  if (MODE == 1) {
#pragma unroll
    for (int mi = 0; mi < MFR; mi++)
#pragma unroll
      for (int ni = 0; ni < 4; ni++) {
        int col = blockIdx.y * 128 + wn * 64 + ni * 16 + (lane & 15);
        float bb = bq[col];
#pragma unroll
        for (int g = 0; g < 4; g++) {
          int rr = rowb + mi * 16 + g;
          oOut[(size_t)rr * 512 + col] = acc[mi][ni][g] + bb;
        }
      }
    return;
  }
  const int region = blockIdx.y >> 2;                 // 0=Q 1=K 2=V
  const float* bias = (region == 0) ? bq : (region == 1) ? bk : bv;
  const int cm0 = (blockIdx.y & 3) * 128;
#pragma unroll
  for (int mi = 0; mi < MFR; mi++)
#pragma unroll
    for (int ni = 0; ni < 4; ni++) {
      int c = cm0 + wn * 64 + ni * 16 + (lane & 15);
      float bb = bias[c];
      if (region == 2) {
#pragma unroll
        for (int g = 0; g < 4; g++) {
          int rr = rowb + mi * 16 + g;
          int b = rr >> 11, s = rr & 2047;
          oVT[((size_t)b * 512 + c) * SP + PAD + s] = (bf16)(acc[mi][ni][g] + bb);
        }
      } else {
        int j = c >> 1, par = c & 1;
#pragma unroll
        for (int g = 0; g < 4; g++) {
          int rr = rowb + mi * 16 + g;
          int s = rr & 2047;
          float v = acc[mi][ni][g] + bb;
          float p = __shfl_xor(v, 1);
          float es = sinT[s * 256 + j], ec = cosT[s * 256 + j];
          float res = par ? (p * es + v * ec) : (v * ec - p * es);
          int oc = par ? (j + 256) : j;
          if (region == 0) oQ[(size_t)rr * 512 + oc] = (bf16)res;
          else { int b = rr >> 11; oK[((size_t)b * SP + PAD + s) * 512 + oc] = (bf16)res; }
        }
      }
    }
}

// ---------------- banded MFMA attention, double-buffered ----------------
// grid (128, 2): block = 32 queries x 256 output h-cols (y half).
// Phase 1: S = Q K^T, Q/K dbuf via gload_lds (T3 recipe as gemm_k)
// Phase 2: banded softmax -> P bf16 at 49152
// Phase 3: out = P V, 4 chunks of 64 h-rows, V register-staged (T14
//          issue-early/write-late), dbuf 2x21504 at base 0.
// LDS: QA[0,4K) QB[4K,8K) KA[8K,28K) KB[28K,48K) | scores[0,21K) after p1
//      P[49152,59904) | V dbuf [0,43008)
__global__ __launch_bounds__(256) void attn_mfma_k(
    const bf16* __restrict__ rQb, const bf16* __restrict__ pKb,
    const bf16* __restrict__ pVT, bf16* __restrict__ ab)
{
  __shared__ __align__(16) unsigned char smem[59904];
  const int tid = threadIdx.x, lane = tid & 63, w = tid >> 6;
  const int q0g = blockIdx.x * TQ;
  const int nbase = blockIdx.y * 256;
  const int b = q0g >> 11, s0 = q0g & 2047;
  const int lr = lane & 15, lk = lane >> 4;
  const int OFF_P = 49152;

  // ---- phase 1: scores (Q/K double-buffered)
  f32x4 sacc[5] = {};
  const int tm = w >> 1, tnb = (w & 1) * 5;

  auto stageQK = [&](int k0, int sel) {
    {   // Q: 32 rows x 8 slots (128B/row), linear dest
      int r = tid >> 3, p = tid & 7, l = p ^ (r & 7);
      GLDS16(rQb + (size_t)(q0g + r) * 512 + k0 + l * 8,
             smem + sel * 4096 + tid * 16);
    }
#pragma unroll
    for (int i = 0; i < 5; i++) {  // K: 160 rows x 8 slots
      int c = tid + i * 256;
      int r = c >> 3, p = c & 7, l = p ^ (r & 7);
      GLDS16(pKb + ((size_t)b * SP + s0 + r) * 512 + k0 + l * 8,
             smem + 8192 + sel * 20480 + c * 16);
    }
  };

  stageQK(0, 0);
  __syncthreads();
  for (int t = 0; t < 8; t++) {
    if (t < 7) stageQK((t + 1) * 64, (t + 1) & 1);
    const unsigned char* qb = smem + (t & 1) * 4096;
    const unsigned char* kb = smem + 8192 + (t & 1) * 20480;
    __builtin_amdgcn_s_setprio(1);
#pragma unroll
    for (int kk = 0; kk < 2; kk++) {
      int arow = tm * 16 + lr;
      bf16x8 a = *(const bf16x8*)(qb + arow * 128 + (((kk * 64 + lk * 16) ^ ((arow & 7) << 4))));
#pragma unroll
      for (int i = 0; i < 5; i++) {
        int brow = (tnb + i) * 16 + lr;
        bf16x8 bb = *(const bf16x8*)(kb + brow * 128 + (((kk * 64 + lk * 16) ^ ((brow & 7) << 4))));
        sacc[i] = __builtin_amdgcn_mfma_f32_16x16x32_bf16(a, bb, sacc[i], 0, 0, 0);
      }
    }
    __builtin_amdgcn_s_setprio(0);
    __syncthreads();
  }
  {   // write scores f32 [32][164] (QA/QB/KA region now dead)
    float* sc = (float*)smem;
#pragma unroll
    for (int i = 0; i < 5; i++) {
      int col = (tnb + i) * 16 + lr;
#pragma unroll
      for (int g = 0; g < 4; g++) {
        int row = tm * 16 + lk * 4 + g;
        sc[row * 164 + col] = sacc[i][g] * SCALE;
      }
    }
  }
  __syncthreads();
  // ---- phase 2: banded softmax, 8 threads per row
  {
    float* sc = (float*)smem;
    bf16* P = (bf16*)(smem + OFF_P);
    int row = tid >> 3, j0 = tid & 7;
    float vals[20];
    float mx = -1e30f;
#pragma unroll
    for (int i = 0; i < 20; i++) {
      int j = j0 + i * 8;
      bool valid = (j >= row) && (j <= row + 127);
      float v = valid ? sc[row * 164 + j] : -1e30f;
      vals[i] = v;
      mx = fmaxf(mx, v);
    }
#pragma unroll
    for (int off = 1; off < 8; off <<= 1) mx = fmaxf(mx, __shfl_xor(mx, off));
    float sum = 0.f;
#pragma unroll
    for (int i = 0; i < 20; i++) {
      float e = (vals[i] > -1e29f) ? __expf(vals[i] - mx) : 0.f;
      vals[i] = e; sum += e;
    }
#pragma unroll
    for (int off = 1; off < 8; off <<= 1) sum += __shfl_xor(sum, off);
    float inv = 1.f / sum;
#pragma unroll
    for (int i = 0; i < 20; i++) {
      int j = j0 + i * 8;
      P[row * 168 + j] = (bf16)(vals[i] * inv);   // row stride 336B
    }
  }
  // ---- phase 3: out = P @ V, 4 chunks of 64 h-rows, V reg-staged dbuf
  const bf16* pVTb = pVT + (size_t)b * 512 * SP;
  const int vr = tid >> 2, vq = tid & 3;          // 64 rows x 4 thr/row
  float4 vreg[5];
  auto loadV = [&](int n0) {
    const bf16* src = pVTb + (size_t)(n0 + vr) * SP + s0;
#pragma unroll
    for (int i = 0; i < 5; i++)
      vreg[i] = *(const float4*)(src + (vq * 5 + i) * 8);
  };
  auto writeV = [&](int sel) {
    unsigned char* dst = smem + sel * 21504 + vr * 336;
#pragma unroll
    for (int i = 0; i < 5; i++)
      *(float4*)(dst + (vq * 5 + i) * 16) = vreg[i];
  };

  loadV(nbase);            // issue before barrier: latency hides under sync
  __syncthreads();         // all score reads done -> V region reusable
  writeV(0);
  __syncthreads();
  const int cp = w & 1;    // col pair, rows utm
  const int utm = w >> 1;
  for (int c = 0; c < 4; c++) {
    int n0 = nbase + c * 64;
    if (c < 3) loadV(n0 + 64);
    const unsigned char* vb = smem + (c & 1) * 21504;
    f32x4 oacc[2] = {};
    __builtin_amdgcn_s_setprio(1);
#pragma unroll
    for (int tk = 0; tk < 5; tk++) {
      bf16x8 a = *(const bf16x8*)(smem + OFF_P + (utm * 16 + lr) * 336 + tk * 64 + lk * 16);
#pragma unroll
      for (int i = 0; i < 2; i++) {
        int brow = cp * 32 + i * 16 + lr;
        bf16x8 bb = *(const bf16x8*)(vb + brow * 336 + tk * 64 + lk * 16);
        oacc[i] = __builtin_amdgcn_mfma_f32_16x16x32_bf16(a, bb, oacc[i], 0, 0, 0);
      }
    }
    __builtin_amdgcn_s_setprio(0);
    if (c < 3) writeV((c + 1) & 1);
#pragma unroll
    for (int i = 0; i < 2; i++) {
      int col = n0 + (cp * 2 + i) * 16 + lr;
#pragma unroll
      for (int g = 0; g < 4; g++) {
        int row = utm * 16 + lk * 4 + g;
        ab[(size_t)(q0g + row) * 512 + col] = (bf16)oacc[i][g];
      }
    }
    __syncthreads();
  }
}

// ---------------- launch -------------------------------------------------
extern "C" void kernel_launch(void* const* d_in, const int* in_sizes, int n_in,
                              void* d_out, int out_size, void* d_ws, size_t ws_size,
                              hipStream_t stream) {
  const float* x  = (const float*)d_in[0];
  const float* Wq = (const float*)d_in[1];
  const float* bq = (const float*)d_in[2];
  const float* Wk = (const float*)d_in[3];
  const float* bk = (const float*)d_in[4];
  const float* Wv = (const float*)d_in[5];
  const float* bv = (const float*)d_in[6];
  const float* Wo = (const float*)d_in[7];
  const float* bo = (const float*)d_in[8];
  float* out = (float*)d_out;

  const size_t NQ = (size_t)B_SZ * S_LEN * H_DIM;  // 2,097,152
  const size_t NP = (size_t)B_SZ * SP * H_DIM;     // 2,228,224
  float* sinT = (float*)d_ws;                      // 524288 f32
  float* cosT = sinT + (size_t)S_LEN * 256;        // 524288 f32
  bf16* xb  = (bf16*)(cosT + (size_t)S_LEN * 256); // NQ
  bf16* wb  = xb + NQ;                             // 2048*512
  bf16* rQb = wb + 2048 * 512;                     // NQ
  bf16* pKb = rQb + NQ;                            // NP
  bf16* pVT = pKb + NP;                            // NP
  bf16* ab  = pVT + NP;                            // NQ

  prep_k<<<3200, 256, 0, stream>>>(x, Wq, Wk, Wv, Wo, xb, wb,
                                   pKb, pVT, sinT, cosT);

  gemm_k<4, 0><<<dim3(32, 12), 256, 0, stream>>>(xb, wb,
      bq, bk, bv, sinT, cosT, rQb, pKb, pVT, nullptr);

  attn_mfma_k<<<dim3(B_SZ * S_LEN / TQ, 2), 256, 0, stream>>>(rQb, pKb, pVT, ab);

  gemm_k<2, 1><<<dim3(64, 4), 256, 0, stream>>>(ab, wb,
      bo, nullptr, nullptr, sinT, cosT, nullptr, nullptr, nullptr, out);
}

// Round 12
// 47.602 us; speedup vs baseline: 1.5045x; 1.5045x over previous
//
#include <hip/hip_runtime.h>
#include <math.h>

#define S_LEN 2048
#define B_SZ  2
#define H_DIM 512
#define WIN   128
#define PAD   64
#define SP    (S_LEN + WIN)   /* 2176 padded seq length */
#define SCALE 0.044194173824159216f  /* 1/sqrt(512) */
#define TQ    32

typedef __bf16 bf16;
typedef __attribute__((ext_vector_type(8))) __bf16 bf16x8;
typedef __attribute__((ext_vector_type(4))) __bf16 bf16x4;
typedef __attribute__((ext_vector_type(4))) float f32x4;

#define GLDS16(g, l) __builtin_amdgcn_global_load_lds( \
    (const __attribute__((address_space(1))) void*)(g), \
    (__attribute__((address_space(3))) void*)(l), 16, 0, 0)

// ---------------- fused prep: x->bf16 | W->bf16 | pads | rope tables ----
__global__ __launch_bounds__(256) void prep_k(
    const float* __restrict__ x,
    const float* __restrict__ Wq, const float* __restrict__ Wk,
    const float* __restrict__ Wv, const float* __restrict__ Wo,
    bf16* __restrict__ xb, bf16* __restrict__ wb,
    bf16* __restrict__ pKb, bf16* __restrict__ pVT,
    float* __restrict__ sinT, float* __restrict__ cosT)
{
  int i = blockIdx.x * 256 + threadIdx.x;
  if (i < 262144) {                     // R0: x -> bf16
    int e = i * 8;
    float4 v0 = *(const float4*)(x + e);
    float4 v1 = *(const float4*)(x + e + 4);
    bf16x8 o = {(bf16)v0.x, (bf16)v0.y, (bf16)v0.z, (bf16)v0.w,
                (bf16)v1.x, (bf16)v1.y, (bf16)v1.z, (bf16)v1.w};
    *(bf16x8*)(xb + e) = o;
  } else if (i < 524288) {              // R1: weights -> bf16 (1-pass)
    int idx = (i - 262144) * 4;
    int m = idx >> 18;
    const float* src = (m == 0) ? Wq : (m == 1) ? Wk : (m == 2) ? Wv : Wo;
    float4 v = *(const float4*)(src + (idx & 262143));
    bf16x4 hv = {(bf16)v.x, (bf16)v.y, (bf16)v.z, (bf16)v.w};
    *(bf16x4*)(wb + idx) = hv;
  } else if (i < 557056) {              // R2: pads
    int idx = i - 524288;
    float4 z = {0.f, 0.f, 0.f, 0.f};
    if (idx < 16384) {        // pKb: 2b x 128 pad-rows x 512 cols
      int b = idx >> 13, r = (idx & 8191) >> 6, c = idx & 63;
      int row = (r < 64) ? r : (S_LEN + r);
      *(float4*)(pKb + ((size_t)b * SP + row) * 512 + c * 8) = z;
    } else {                  // pVT: 2b x 512 rows x 128 pad-cols
      int j = idx - 16384;
      int b = j >> 13, h = (j & 8191) >> 4, v = j & 15;
      int col = (v < 8) ? v * 8 : (S_LEN + PAD + (v - 8) * 8);
      *(float4*)(pVT + ((size_t)b * 512 + h) * SP + col) = z;
    }
  } else {                              // R3: rope tables
    int idx = i - 557056;               // [0, 262144) = s*128 + jj
    int s = idx >> 7, jj = idx & 127;
    float fqA = exp2f(-(float)jj * 0.10381025296523f);          // i = 2jj
    float fqB = exp2f(-(float)(2 * jj + 1) * 0.05190512648262f); // i = 2jj+1
    float aA = (float)s * fqA;
    float aB = (float)s * fqB;
    sinT[s * 256 + jj]       = sinf(aA);
    sinT[s * 256 + jj + 128] = cosf(aA);
    cosT[s * 256 + jj]       = sinf(aB);
    cosT[s * 256 + jj + 128] = cosf(aB);
  }
}

// ---------------- 1-pass bf16 MFMA GEMM, BK=64 (round-10 verified) ------
template<int MFR, int MODE>
__global__ __launch_bounds__(256) void gemm_k(
    const bf16* __restrict__ Ab, const bf16* __restrict__ Wb,
    const float* __restrict__ bq, const float* __restrict__ bk,
    const float* __restrict__ bv,
    const float* __restrict__ sinT, const float* __restrict__ cosT,
    bf16* __restrict__ oQ, bf16* __restrict__ oK, bf16* __restrict__ oVT,
    float* __restrict__ oOut)
{
  constexpr int BM = MFR * 32;
  constexpr int ABYTES = BM * 128;
  constexpr int BUFB = ABYTES + 128 * 128;
  __shared__ __align__(16) unsigned char smem[2 * BUFB];
  const int tid = threadIdx.x;
  const int lane = tid & 63, wid = tid >> 6;
  const int wm = wid >> 1, wn = wid & 1;
  const int row0 = blockIdx.x * BM;
  const int wrow0 = (MODE == 0 ? 0 : 1536) + blockIdx.y * 128;
  const int lr = lane & 15, lk = lane >> 4;

  f32x4 acc[MFR][4] = {};

  auto stage = [&](int k0, int bufsel) {
    unsigned char* buf = smem + bufsel * BUFB;
#pragma unroll
    for (int i = 0; i < MFR; i++) {         // A: BM rows x 8 slots of 16B
      int c = tid + i * 256;
      int r = c >> 3, p = c & 7, l = p ^ (r & 7);
      GLDS16(Ab + (size_t)(row0 + r) * 512 + k0 + l * 8, buf + c * 16);
    }
#pragma unroll
    for (int j = 0; j < 4; j++) {           // B: 128 rows x 8 slots of 16B
      int c = tid + j * 256;
      int r = c >> 3, p = c & 7, l = p ^ (r & 7);
      GLDS16(Wb + (size_t)(wrow0 + r) * 512 + k0 + l * 8, buf + ABYTES + c * 16);
    }
  };

  stage(0, 0);
  __syncthreads();
  for (int t = 0; t < 8; t++) {
    if (t < 7) stage((t + 1) * 64, (t + 1) & 1);
    const unsigned char* buf = smem + (t & 1) * BUFB;
    bf16x8 bfr[4][2];
#pragma unroll
    for (int ni = 0; ni < 4; ni++) {
      int r = wn * 64 + ni * 16 + lr;
      const unsigned char* base = buf + ABYTES + r * 128;
      int sw = (r & 7) << 4;
      bfr[ni][0] = *(const bf16x8*)(base + ((lk * 16) ^ sw));
      bfr[ni][1] = *(const bf16x8*)(base + ((64 + lk * 16) ^ sw));
    }
#pragma unroll
    for (int mi = 0; mi < MFR; mi++) {
      int r = wm * (MFR * 16) + mi * 16 + lr;
      const unsigned char* base = buf + r * 128;
      int sw = (r & 7) << 4;
      bf16x8 a0 = *(const bf16x8*)(base + ((lk * 16) ^ sw));
      bf16x8 a1 = *(const bf16x8*)(base + ((64 + lk * 16) ^ sw));
#pragma unroll
      for (int ni = 0; ni < 4; ni++) {
        acc[mi][ni] = __builtin_amdgcn_mfma_f32_16x16x32_bf16(a0, bfr[ni][0], acc[mi][ni], 0, 0, 0);
        acc[mi][ni] = __builtin_amdgcn_mfma_f32_16x16x32_bf16(a1, bfr[ni][1], acc[mi][ni], 0, 0, 0);
      }
    }
    __syncthreads();
  }

  const int rowb = row0 + wm * (MFR * 16) + ((lane >> 4) * 4);
  if (MODE == 1) {
#pragma unroll
    for (int mi = 0; mi < MFR; mi++)
#pragma unroll
      for (int ni = 0; ni < 4; ni++) {
        int col = blockIdx.y * 128 + wn * 64 + ni * 16 + (lane & 15);
        float bb = bq[col];
#pragma unroll
        for (int g = 0; g < 4; g++) {
          int rr = rowb + mi * 16 + g;
          oOut[(size_t)rr * 512 + col] = acc[mi][ni][g] + bb;
        }
      }
    return;
  }
  const int region = blockIdx.y >> 2;                 // 0=Q 1=K 2=V
  const float* bias = (region == 0) ? bq : (region == 1) ? bk : bv;
  const int cm0 = (blockIdx.y & 3) * 128;
#pragma unroll
  for (int mi = 0; mi < MFR; mi++)
#pragma unroll
    for (int ni = 0; ni < 4; ni++) {
      int c = cm0 + wn * 64 + ni * 16 + (lane & 15);
      float bb = bias[c];
      if (region == 2) {
#pragma unroll
        for (int g = 0; g < 4; g++) {
          int rr = rowb + mi * 16 + g;
          int b = rr >> 11, s = rr & 2047;
          oVT[((size_t)b * 512 + c) * SP + PAD + s] = (bf16)(acc[mi][ni][g] + bb);
        }
      } else {
        int j = c >> 1, par = c & 1;
#pragma unroll
        for (int g = 0; g < 4; g++) {
          int rr = rowb + mi * 16 + g;
          int s = rr & 2047;
          float v = acc[mi][ni][g] + bb;
          float p = __shfl_xor(v, 1);
          float es = sinT[s * 256 + j], ec = cosT[s * 256 + j];
          float res = par ? (p * es + v * ec) : (v * ec - p * es);
          int oc = par ? (j + 256) : j;
          if (region == 0) oQ[(size_t)rr * 512 + oc] = (bf16)res;
          else { int b = rr >> 11; oK[((size_t)b * SP + PAD + s) * 512 + oc] = (bf16)res; }
        }
      }
    }
}

// ---------------- banded MFMA attention (round-10 base, phase-1 dbuf) ---
// grid (128, 2): block = 32 queries x 256 output h-cols (y half).
// Phase 1: S = Q K^T, Q/K double-buffered, ONE barrier/iter, LDS
//          QA[0,4K) QB[4K,8K) KA[8K,28672) KB[28672,49152).
// Phase 2: banded softmax; scores f32 [0,21K) (staging dead); P at 43008
//          (overlaps only dead KB).
// Phase 3: out = P V — byte-identical to round 10: V [0,43008) stride 336.
// Total LDS 53760 -> 3 blocks/CU (unchanged from round 10).
__global__ __launch_bounds__(256) void attn_mfma_k(
    const bf16* __restrict__ rQb, const bf16* __restrict__ pKb,
    const bf16* __restrict__ pVT, bf16* __restrict__ ab)
{
  __shared__ __align__(16) unsigned char smem[53760];
  const int tid = threadIdx.x, lane = tid & 63, w = tid >> 6;
  const int q0g = blockIdx.x * TQ;
  const int nbase = blockIdx.y * 256;
  const int b = q0g >> 11, s0 = q0g & 2047;
  const int lr = lane & 15, lk = lane >> 4;
  const int OFF_K = 8192, OFF_P = 43008;

  // ---- phase 1: scores (Q/K double-buffered, one barrier per iter)
  f32x4 sacc[5] = {};
  const int tm = w >> 1, tnb = (w & 1) * 5;

  auto stageQK = [&](int k0, int sel) {
    {   // Q: 32 rows x 8 slots (128B/row), linear dest
      int r = tid >> 3, p = tid & 7, l = p ^ (r & 7);
      GLDS16(rQb + (size_t)(q0g + r) * 512 + k0 + l * 8,
             smem + sel * 4096 + tid * 16);
    }
#pragma unroll
    for (int i = 0; i < 5; i++) {  // K: 160 rows x 8 slots
      int c = tid + i * 256;
      int r = c >> 3, p = c & 7, l = p ^ (r & 7);
      GLDS16(pKb + ((size_t)b * SP + s0 + r) * 512 + k0 + l * 8,
             smem + OFF_K + sel * 20480 + c * 16);
    }
  };

  stageQK(0, 0);
  __syncthreads();
  for (int t = 0; t < 8; t++) {
    if (t < 7) stageQK((t + 1) * 64, (t + 1) & 1);
    const unsigned char* qb = smem + (t & 1) * 4096;
    const unsigned char* kb = smem + OFF_K + (t & 1) * 20480;
    __builtin_amdgcn_s_setprio(1);
#pragma unroll
    for (int kk = 0; kk < 2; kk++) {
      int arow = tm * 16 + lr;
      bf16x8 a = *(const bf16x8*)(qb + arow * 128 + (((kk * 64 + lk * 16) ^ ((arow & 7) << 4))));
#pragma unroll
      for (int i = 0; i < 5; i++) {
        int brow = (tnb + i) * 16 + lr;
        bf16x8 bb = *(const bf16x8*)(kb + brow * 128 + (((kk * 64 + lk * 16) ^ ((brow & 7) << 4))));
        sacc[i] = __builtin_amdgcn_mfma_f32_16x16x32_bf16(a, bb, sacc[i], 0, 0, 0);
      }
    }
    __builtin_amdgcn_s_setprio(0);
    __syncthreads();
  }
  {   // write scores f32 [32][164] (QA/QB/KA region now dead)
    float* sc = (float*)smem;
#pragma unroll
    for (int i = 0; i < 5; i++) {
      int col = (tnb + i) * 16 + lr;
#pragma unroll
      for (int g = 0; g < 4; g++) {
        int row = tm * 16 + lk * 4 + g;
        sc[row * 164 + col] = sacc[i][g] * SCALE;
      }
    }
  }
  __syncthreads();
  // ---- phase 2: banded softmax, 8 threads per row
  {
    float* sc = (float*)smem;
    bf16* P = (bf16*)(smem + OFF_P);
    int row = tid >> 3, j0 = tid & 7;
    float vals[20];
    float mx = -1e30f;
#pragma unroll
    for (int i = 0; i < 20; i++) {
      int j = j0 + i * 8;
      bool valid = (j >= row) && (j <= row + 127);
      float v = valid ? sc[row * 164 + j] : -1e30f;
      vals[i] = v;
      mx = fmaxf(mx, v);
    }
#pragma unroll
    for (int off = 1; off < 8; off <<= 1) mx = fmaxf(mx, __shfl_xor(mx, off));
    float sum = 0.f;
#pragma unroll
    for (int i = 0; i < 20; i++) {
      float e = (vals[i] > -1e29f) ? __expf(vals[i] - mx) : 0.f;
      vals[i] = e; sum += e;
    }
#pragma unroll
    for (int off = 1; off < 8; off <<= 1) sum += __shfl_xor(sum, off);
    float inv = 1.f / sum;
#pragma unroll
    for (int i = 0; i < 20; i++) {
      int j = j0 + i * 8;
      P[row * 168 + j] = (bf16)(vals[i] * inv);   // row stride 336B
    }
  }
  // ---- phase 3: out = P @ V (round-10 verified path)
  const bf16* pVTb = pVT + (size_t)b * 512 * SP;
  const int utm = w >> 1, utnb = (w & 1) * 4;
  for (int n0 = nbase; n0 < nbase + 256; n0 += 128) {
    __syncthreads();
    {   // stage V chunk: 128 h-rows x 160 keys, LDS row stride 336B
      int r = tid >> 1, half = tid & 1;
      const bf16* src = pVTb + (size_t)(n0 + r) * SP + s0;
#pragma unroll
      for (int i = 0; i < 10; i++) {
        int slot = half * 10 + i;
        float4 v = *(const float4*)(src + slot * 8);
        *(float4*)(smem + r * 336 + slot * 16) = v;
      }
    }
    __syncthreads();
    f32x4 oacc[4] = {};
    __builtin_amdgcn_s_setprio(1);
#pragma unroll
    for (int tk = 0; tk < 5; tk++) {
      int arow = utm * 16 + lr;
      bf16x8 a = *(const bf16x8*)(smem + OFF_P + arow * 336 + tk * 64 + lk * 16);
#pragma unroll
      for (int i = 0; i < 4; i++) {
        int brow = (utnb + i) * 16 + lr;
        bf16x8 bb = *(const bf16x8*)(smem + brow * 336 + tk * 64 + lk * 16);
        oacc[i] = __builtin_amdgcn_mfma_f32_16x16x32_bf16(a, bb, oacc[i], 0, 0, 0);
      }
    }
    __builtin_amdgcn_s_setprio(0);
#pragma unroll
    for (int i = 0; i < 4; i++) {
      int col = n0 + (utnb + i) * 16 + lr;
#pragma unroll
      for (int g = 0; g < 4; g++) {
        int row = utm * 16 + lk * 4 + g;
        ab[(size_t)(q0g + row) * 512 + col] = (bf16)oacc[i][g];
      }
    }
  }
}

// ---------------- launch -------------------------------------------------
extern "C" void kernel_launch(void* const* d_in, const int* in_sizes, int n_in,
                              void* d_out, int out_size, void* d_ws, size_t ws_size,
                              hipStream_t stream) {
  const float* x  = (const float*)d_in[0];
  const float* Wq = (const float*)d_in[1];
  const float* bq = (const float*)d_in[2];
  const float* Wk = (const float*)d_in[3];
  const float* bk = (const float*)d_in[4];
  const float* Wv = (const float*)d_in[5];
  const float* bv = (const float*)d_in[6];
  const float* Wo = (const float*)d_in[7];
  const float* bo = (const float*)d_in[8];
  float* out = (float*)d_out;

  const size_t NQ = (size_t)B_SZ * S_LEN * H_DIM;  // 2,097,152
  const size_t NP = (size_t)B_SZ * SP * H_DIM;     // 2,228,224
  float* sinT = (float*)d_ws;                      // 524288 f32
  float* cosT = sinT + (size_t)S_LEN * 256;        // 524288 f32
  bf16* xb  = (bf16*)(cosT + (size_t)S_LEN * 256); // NQ
  bf16* wb  = xb + NQ;                             // 2048*512
  bf16* rQb = wb + 2048 * 512;                     // NQ
  bf16* pKb = rQb + NQ;                            // NP
  bf16* pVT = pKb + NP;                            // NP
  bf16* ab  = pVT + NP;                            // NQ

  prep_k<<<3200, 256, 0, stream>>>(x, Wq, Wk, Wv, Wo, xb, wb,
                                   pKb, pVT, sinT, cosT);

  gemm_k<4, 0><<<dim3(32, 12), 256, 0, stream>>>(xb, wb,
      bq, bk, bv, sinT, cosT, rQb, pKb, pVT, nullptr);

  attn_mfma_k<<<dim3(B_SZ * S_LEN / TQ, 2), 256, 0, stream>>>(rQb, pKb, pVT, ab);

  gemm_k<2, 1><<<dim3(64, 4), 256, 0, stream>>>(ab, wb,
      bo, nullptr, nullptr, sinT, cosT, nullptr, nullptr, nullptr, out);
}

// Round 13
// 46.002 us; speedup vs baseline: 1.5568x; 1.0348x over previous
//
#include <hip/hip_runtime.h>
#include <math.h>

#define S_LEN 2048
#define B_SZ  2
#define H_DIM 512
#define WIN   128
#define PAD   64
#define SP    (S_LEN + WIN)   /* 2176 padded seq length */
#define SCALE 0.044194173824159216f  /* 1/sqrt(512) */
#define TQ    32

typedef __bf16 bf16;
typedef __attribute__((ext_vector_type(8))) __bf16 bf16x8;
typedef __attribute__((ext_vector_type(4))) __bf16 bf16x4;
typedef __attribute__((ext_vector_type(4))) float f32x4;

#define GLDS16(g, l) __builtin_amdgcn_global_load_lds( \
    (const __attribute__((address_space(1))) void*)(g), \
    (__attribute__((address_space(3))) void*)(l), 16, 0, 0)

// ---------------- fused prep: x->bf16 | W->bf16 | pads | rope tables ----
__global__ __launch_bounds__(256) void prep_k(
    const float* __restrict__ x,
    const float* __restrict__ Wq, const float* __restrict__ Wk,
    const float* __restrict__ Wv, const float* __restrict__ Wo,
    bf16* __restrict__ xb, bf16* __restrict__ wb,
    bf16* __restrict__ pKb, bf16* __restrict__ pVT,
    float* __restrict__ sinT, float* __restrict__ cosT)
{
  int i = blockIdx.x * 256 + threadIdx.x;
  if (i < 262144) {                     // R0: x -> bf16
    int e = i * 8;
    float4 v0 = *(const float4*)(x + e);
    float4 v1 = *(const float4*)(x + e + 4);
    bf16x8 o = {(bf16)v0.x, (bf16)v0.y, (bf16)v0.z, (bf16)v0.w,
                (bf16)v1.x, (bf16)v1.y, (bf16)v1.z, (bf16)v1.w};
    *(bf16x8*)(xb + e) = o;
  } else if (i < 524288) {              // R1: weights -> bf16 (1-pass)
    int idx = (i - 262144) * 4;
    int m = idx >> 18;
    const float* src = (m == 0) ? Wq : (m == 1) ? Wk : (m == 2) ? Wv : Wo;
    float4 v = *(const float4*)(src + (idx & 262143));
    bf16x4 hv = {(bf16)v.x, (bf16)v.y, (bf16)v.z, (bf16)v.w};
    *(bf16x4*)(wb + idx) = hv;
  } else if (i < 557056) {              // R2: pads
    int idx = i - 524288;
    float4 z = {0.f, 0.f, 0.f, 0.f};
    if (idx < 16384) {        // pKb: 2b x 128 pad-rows x 512 cols
      int b = idx >> 13, r = (idx & 8191) >> 6, c = idx & 63;
      int row = (r < 64) ? r : (S_LEN + r);
      *(float4*)(pKb + ((size_t)b * SP + row) * 512 + c * 8) = z;
    } else {                  // pVT: 2b x 512 rows x 128 pad-cols
      int j = idx - 16384;
      int b = j >> 13, h = (j & 8191) >> 4, v = j & 15;
      int col = (v < 8) ? v * 8 : (S_LEN + PAD + (v - 8) * 8);
      *(float4*)(pVT + ((size_t)b * 512 + h) * SP + col) = z;
    }
  } else {                              // R3: rope tables
    int idx = i - 557056;               // [0, 262144) = s*128 + jj
    int s = idx >> 7, jj = idx & 127;
    float fqA = exp2f(-(float)jj * 0.10381025296523f);          // i = 2jj
    float fqB = exp2f(-(float)(2 * jj + 1) * 0.05190512648262f); // i = 2jj+1
    float aA = (float)s * fqA;
    float aB = (float)s * fqB;
    sinT[s * 256 + jj]       = sinf(aA);
    sinT[s * 256 + jj + 128] = cosf(aA);
    cosT[s * 256 + jj]       = sinf(aB);
    cosT[s * 256 + jj + 128] = cosf(aB);
  }
}

// ---------------- 1-pass bf16 MFMA GEMM, BK=64 (round-10 verified) ------
template<int MFR, int MODE>
__global__ __launch_bounds__(256) void gemm_k(
    const bf16* __restrict__ Ab, const bf16* __restrict__ Wb,
    const float* __restrict__ bq, const float* __restrict__ bk,
    const float* __restrict__ bv,
    const float* __restrict__ sinT, const float* __restrict__ cosT,
    bf16* __restrict__ oQ, bf16* __restrict__ oK, bf16* __restrict__ oVT,
    float* __restrict__ oOut)
{
  constexpr int BM = MFR * 32;
  constexpr int ABYTES = BM * 128;
  constexpr int BUFB = ABYTES + 128 * 128;
  __shared__ __align__(16) unsigned char smem[2 * BUFB];
  const int tid = threadIdx.x;
  const int lane = tid & 63, wid = tid >> 6;
  const int wm = wid >> 1, wn = wid & 1;
  const int row0 = blockIdx.x * BM;
  const int wrow0 = (MODE == 0 ? 0 : 1536) + blockIdx.y * 128;
  const int lr = lane & 15, lk = lane >> 4;

  f32x4 acc[MFR][4] = {};

  auto stage = [&](int k0, int bufsel) {
    unsigned char* buf = smem + bufsel * BUFB;
#pragma unroll
    for (int i = 0; i < MFR; i++) {         // A: BM rows x 8 slots of 16B
      int c = tid + i * 256;
      int r = c >> 3, p = c & 7, l = p ^ (r & 7);
      GLDS16(Ab + (size_t)(row0 + r) * 512 + k0 + l * 8, buf + c * 16);
    }
#pragma unroll
    for (int j = 0; j < 4; j++) {           // B: 128 rows x 8 slots of 16B
      int c = tid + j * 256;
      int r = c >> 3, p = c & 7, l = p ^ (r & 7);
      GLDS16(Wb + (size_t)(wrow0 + r) * 512 + k0 + l * 8, buf + ABYTES + c * 16);
    }
  };

  stage(0, 0);
  __syncthreads();
  for (int t = 0; t < 8; t++) {
    if (t < 7) stage((t + 1) * 64, (t + 1) & 1);
    const unsigned char* buf = smem + (t & 1) * BUFB;
    bf16x8 bfr[4][2];
#pragma unroll
    for (int ni = 0; ni < 4; ni++) {
      int r = wn * 64 + ni * 16 + lr;
      const unsigned char* base = buf + ABYTES + r * 128;
      int sw = (r & 7) << 4;
      bfr[ni][0] = *(const bf16x8*)(base + ((lk * 16) ^ sw));
      bfr[ni][1] = *(const bf16x8*)(base + ((64 + lk * 16) ^ sw));
    }
#pragma unroll
    for (int mi = 0; mi < MFR; mi++) {
      int r = wm * (MFR * 16) + mi * 16 + lr;
      const unsigned char* base = buf + r * 128;
      int sw = (r & 7) << 4;
      bf16x8 a0 = *(const bf16x8*)(base + ((lk * 16) ^ sw));
      bf16x8 a1 = *(const bf16x8*)(base + ((64 + lk * 16) ^ sw));
#pragma unroll
      for (int ni = 0; ni < 4; ni++) {
        acc[mi][ni] = __builtin_amdgcn_mfma_f32_16x16x32_bf16(a0, bfr[ni][0], acc[mi][ni], 0, 0, 0);
        acc[mi][ni] = __builtin_amdgcn_mfma_f32_16x16x32_bf16(a1, bfr[ni][1], acc[mi][ni], 0, 0, 0);
      }
    }
    __syncthreads();
  }

  const int rowb = row0 + wm * (MFR * 16) + ((lane >> 4) * 4);
  if (MODE == 1) {
#pragma unroll
    for (int mi = 0; mi < MFR; mi++)
#pragma unroll
      for (int ni = 0; ni < 4; ni++) {
        int col = blockIdx.y * 128 + wn * 64 + ni * 16 + (lane & 15);
        float bb = bq[col];
#pragma unroll
        for (int g = 0; g < 4; g++) {
          int rr = rowb + mi * 16 + g;
          oOut[(size_t)rr * 512 + col] = acc[mi][ni][g] + bb;
        }
      }
    return;
  }
  const int region = blockIdx.y >> 2;                 // 0=Q 1=K 2=V
  const float* bias = (region == 0) ? bq : (region == 1) ? bk : bv;
  const int cm0 = (blockIdx.y & 3) * 128;
#pragma unroll
  for (int mi = 0; mi < MFR; mi++)
#pragma unroll
    for (int ni = 0; ni < 4; ni++) {
      int c = cm0 + wn * 64 + ni * 16 + (lane & 15);
      float bb = bias[c];
      if (region == 2) {
#pragma unroll
        for (int g = 0; g < 4; g++) {
          int rr = rowb + mi * 16 + g;
          int b = rr >> 11, s = rr & 2047;
          oVT[((size_t)b * 512 + c) * SP + PAD + s] = (bf16)(acc[mi][ni][g] + bb);
        }
      } else {
        int j = c >> 1, par = c & 1;
#pragma unroll
        for (int g = 0; g < 4; g++) {
          int rr = rowb + mi * 16 + g;
          int s = rr & 2047;
          float v = acc[mi][ni][g] + bb;
          float p = __shfl_xor(v, 1);
          float es = sinT[s * 256 + j], ec = cosT[s * 256 + j];
          float res = par ? (p * es + v * ec) : (v * ec - p * es);
          int oc = par ? (j + 256) : j;
          if (region == 0) oQ[(size_t)rr * 512 + oc] = (bf16)res;
          else { int b = rr >> 11; oK[((size_t)b * SP + PAD + s) * 512 + oc] = (bf16)res; }
        }
      }
    }
}

// ---------------- banded MFMA attention, 512 threads, K-split -----------
// grid (128, 2): block = 32 queries x 256 output h-cols (y half), 8 waves.
// Phase 1: two 4-wave groups, group g accumulates k in [g*256, g*256+256)
//   with its own Q/K double-buffer (one barrier/iter, 4 iters). Partial
//   scores -> two f32 arrays, summed (* SCALE) in softmax.
// Phase 2: banded softmax, 16 lanes/row over 512 threads.
// Phase 3: out = P V, 2 chunks of 128 h-rows, 8 waves (2 col-tiles each).
// LDS (98304 total, 1 block/CU — grid has only 1 block/CU anyway):
//   group g staging: [g*49152, g*49152+49152) = Q dbuf 8K + K dbuf 40K
//   scores: g*21504 + [0,20992)   (over dead staging)
//   P: [43008, 53760)             (over dead KB/QA regions)
//   V: [0, 43008)                 (over dead scores/staging)
__global__ __launch_bounds__(512) void attn_mfma_k(
    const bf16* __restrict__ rQb, const bf16* __restrict__ pKb,
    const bf16* __restrict__ pVT, bf16* __restrict__ ab)
{
  __shared__ __align__(16) unsigned char smem[98304];
  const int tid = threadIdx.x, lane = tid & 63, w = tid >> 6;
  const int g = w >> 2, ww = w & 3, gtid = tid & 255;
  const int q0g = blockIdx.x * TQ;
  const int nbase = blockIdx.y * 256;
  const int b = q0g >> 11, s0 = q0g & 2047;
  const int lr = lane & 15, lk = lane >> 4;
  const int GB = g * 49152;
  const int OFF_P = 43008;

  // ---- phase 1: partial scores, K-split across wave groups
  f32x4 sacc[5] = {};
  const int tm = ww >> 1, tnb = (ww & 1) * 5;

  auto stageQK = [&](int k0, int sel) {
    {   // Q: 32 rows x 8 slots (128B/row), linear dest per wave
      int r = gtid >> 3, p = gtid & 7, l = p ^ (r & 7);
      GLDS16(rQb + (size_t)(q0g + r) * 512 + k0 + l * 8,
             smem + GB + sel * 4096 + gtid * 16);
    }
#pragma unroll
    for (int i = 0; i < 5; i++) {  // K: 160 rows x 8 slots
      int c = gtid + i * 256;
      int r = c >> 3, p = c & 7, l = p ^ (r & 7);
      GLDS16(pKb + ((size_t)b * SP + s0 + r) * 512 + k0 + l * 8,
             smem + GB + 8192 + sel * 20480 + c * 16);
    }
  };

  stageQK(g * 256, 0);
  __syncthreads();
  for (int t = 0; t < 4; t++) {
    if (t < 3) stageQK(g * 256 + (t + 1) * 64, (t + 1) & 1);
    const unsigned char* qb = smem + GB + (t & 1) * 4096;
    const unsigned char* kb = smem + GB + 8192 + (t & 1) * 20480;
    __builtin_amdgcn_s_setprio(1);
#pragma unroll
    for (int kk = 0; kk < 2; kk++) {
      int arow = tm * 16 + lr;
      bf16x8 a = *(const bf16x8*)(qb + arow * 128 + (((kk * 64 + lk * 16) ^ ((arow & 7) << 4))));
#pragma unroll
      for (int i = 0; i < 5; i++) {
        int brow = (tnb + i) * 16 + lr;
        bf16x8 bb = *(const bf16x8*)(kb + brow * 128 + (((kk * 64 + lk * 16) ^ ((brow & 7) << 4))));
        sacc[i] = __builtin_amdgcn_mfma_f32_16x16x32_bf16(a, bb, sacc[i], 0, 0, 0);
      }
    }
    __builtin_amdgcn_s_setprio(0);
    __syncthreads();
  }
  {   // write raw partial scores f32 [32][164] at group offset
    float* sc = (float*)(smem + g * 21504);
#pragma unroll
    for (int i = 0; i < 5; i++) {
      int col = (tnb + i) * 16 + lr;
#pragma unroll
      for (int gg = 0; gg < 4; gg++) {
        int row = tm * 16 + lk * 4 + gg;
        sc[row * 164 + col] = sacc[i][gg];
      }
    }
  }
  __syncthreads();
  // ---- phase 2: banded softmax, 16 threads per row (512 threads)
  {
    const float* sA = (const float*)smem;
    const float* sB = (const float*)(smem + 21504);
    bf16* P = (bf16*)(smem + OFF_P);
    int row = tid >> 4, j0 = tid & 15;
    float vals[10];
    float mx = -1e30f;
#pragma unroll
    for (int i = 0; i < 10; i++) {
      int j = j0 + i * 16;
      bool valid = (j >= row) && (j <= row + 127);
      float v = valid ? (sA[row * 164 + j] + sB[row * 164 + j]) * SCALE : -1e30f;
      vals[i] = v;
      mx = fmaxf(mx, v);
    }
#pragma unroll
    for (int off = 1; off < 16; off <<= 1) mx = fmaxf(mx, __shfl_xor(mx, off));
    float sum = 0.f;
#pragma unroll
    for (int i = 0; i < 10; i++) {
      float e = (vals[i] > -1e29f) ? __expf(vals[i] - mx) : 0.f;
      vals[i] = e; sum += e;
    }
#pragma unroll
    for (int off = 1; off < 16; off <<= 1) sum += __shfl_xor(sum, off);
    float inv = 1.f / sum;
#pragma unroll
    for (int i = 0; i < 10; i++)
      P[row * 168 + j0 + i * 16] = (bf16)(vals[i] * inv);   // stride 336B
  }
  // ---- phase 3: out = P @ V, 2 chunks of 128 h-rows, 8 waves
  const bf16* pVTb = pVT + (size_t)b * 512 * SP;
  const int utm = w >> 2, utnb = (w & 3) * 2;
  for (int n0 = nbase; n0 < nbase + 256; n0 += 128) {
    __syncthreads();
    {   // stage V chunk: 128 h-rows x 160 keys, LDS row stride 336B
      int r = tid >> 2, q = tid & 3;
      const bf16* src = pVTb + (size_t)(n0 + r) * SP + s0;
#pragma unroll
      for (int i = 0; i < 5; i++) {
        int slot = q * 5 + i;
        float4 v = *(const float4*)(src + slot * 8);
        *(float4*)(smem + r * 336 + slot * 16) = v;
      }
    }
    __syncthreads();
    f32x4 oacc[2] = {};
    __builtin_amdgcn_s_setprio(1);
#pragma unroll
    for (int tk = 0; tk < 5; tk++) {
      bf16x8 a = *(const bf16x8*)(smem + OFF_P + (utm * 16 + lr) * 336 + tk * 64 + lk * 16);
#pragma unroll
      for (int i = 0; i < 2; i++) {
        int brow = (utnb + i) * 16 + lr;
        bf16x8 bb = *(const bf16x8*)(smem + brow * 336 + tk * 64 + lk * 16);
        oacc[i] = __builtin_amdgcn_mfma_f32_16x16x32_bf16(a, bb, oacc[i], 0, 0, 0);
      }
    }
    __builtin_amdgcn_s_setprio(0);
#pragma unroll
    for (int i = 0; i < 2; i++) {
      int col = n0 + (utnb + i) * 16 + lr;
#pragma unroll
      for (int gg = 0; gg < 4; gg++) {
        int row = utm * 16 + lk * 4 + gg;
        ab[(size_t)(q0g + row) * 512 + col] = (bf16)oacc[i][gg];
      }
    }
  }
}

// ---------------- launch -------------------------------------------------
extern "C" void kernel_launch(void* const* d_in, const int* in_sizes, int n_in,
                              void* d_out, int out_size, void* d_ws, size_t ws_size,
                              hipStream_t stream) {
  const float* x  = (const float*)d_in[0];
  const float* Wq = (const float*)d_in[1];
  const float* bq = (const float*)d_in[2];
  const float* Wk = (const float*)d_in[3];
  const float* bk = (const float*)d_in[4];
  const float* Wv = (const float*)d_in[5];
  const float* bv = (const float*)d_in[6];
  const float* Wo = (const float*)d_in[7];
  const float* bo = (const float*)d_in[8];
  float* out = (float*)d_out;

  const size_t NQ = (size_t)B_SZ * S_LEN * H_DIM;  // 2,097,152
  const size_t NP = (size_t)B_SZ * SP * H_DIM;     // 2,228,224
  float* sinT = (float*)d_ws;                      // 524288 f32
  float* cosT = sinT + (size_t)S_LEN * 256;        // 524288 f32
  bf16* xb  = (bf16*)(cosT + (size_t)S_LEN * 256); // NQ
  bf16* wb  = xb + NQ;                             // 2048*512
  bf16* rQb = wb + 2048 * 512;                     // NQ
  bf16* pKb = rQb + NQ;                            // NP
  bf16* pVT = pKb + NP;                            // NP
  bf16* ab  = pVT + NP;                            // NQ

  prep_k<<<3200, 256, 0, stream>>>(x, Wq, Wk, Wv, Wo, xb, wb,
                                   pKb, pVT, sinT, cosT);

  gemm_k<4, 0><<<dim3(32, 12), 256, 0, stream>>>(xb, wb,
      bq, bk, bv, sinT, cosT, rQb, pKb, pVT, nullptr);

  attn_mfma_k<<<dim3(B_SZ * S_LEN / TQ, 2), 512, 0, stream>>>(rQb, pKb, pVT, ab);

  gemm_k<2, 1><<<dim3(64, 4), 256, 0, stream>>>(ab, wb,
      bo, nullptr, nullptr, sinT, cosT, nullptr, nullptr, nullptr, out);
}

// Round 14
// 44.648 us; speedup vs baseline: 1.6040x; 1.0303x over previous
//
#include <hip/hip_runtime.h>
#include <math.h>

#define S_LEN 2048
#define B_SZ  2
#define H_DIM 512
#define WIN   128
#define PAD   64
#define SP    (S_LEN + WIN)   /* 2176 padded seq length */
#define SCALE 0.044194173824159216f  /* 1/sqrt(512) */
#define TQ    32

typedef __bf16 bf16;
typedef __attribute__((ext_vector_type(8))) __bf16 bf16x8;
typedef __attribute__((ext_vector_type(4))) __bf16 bf16x4;
typedef __attribute__((ext_vector_type(4))) float f32x4;

#define GLDS16(g, l) __builtin_amdgcn_global_load_lds( \
    (const __attribute__((address_space(1))) void*)(g), \
    (__attribute__((address_space(3))) void*)(l), 16, 0, 0)

// ---------------- fused prep: x->bf16 | W->bf16 | pads | rope tables ----
__global__ __launch_bounds__(256) void prep_k(
    const float* __restrict__ x,
    const float* __restrict__ Wq, const float* __restrict__ Wk,
    const float* __restrict__ Wv, const float* __restrict__ Wo,
    bf16* __restrict__ xb, bf16* __restrict__ wb,
    bf16* __restrict__ pKb, bf16* __restrict__ pVT,
    float* __restrict__ sinT, float* __restrict__ cosT)
{
  int i = blockIdx.x * 256 + threadIdx.x;
  if (i < 262144) {                     // R0: x -> bf16
    int e = i * 8;
    float4 v0 = *(const float4*)(x + e);
    float4 v1 = *(const float4*)(x + e + 4);
    bf16x8 o = {(bf16)v0.x, (bf16)v0.y, (bf16)v0.z, (bf16)v0.w,
                (bf16)v1.x, (bf16)v1.y, (bf16)v1.z, (bf16)v1.w};
    *(bf16x8*)(xb + e) = o;
  } else if (i < 524288) {              // R1: weights -> bf16 (1-pass)
    int idx = (i - 262144) * 4;
    int m = idx >> 18;
    const float* src = (m == 0) ? Wq : (m == 1) ? Wk : (m == 2) ? Wv : Wo;
    float4 v = *(const float4*)(src + (idx & 262143));
    bf16x4 hv = {(bf16)v.x, (bf16)v.y, (bf16)v.z, (bf16)v.w};
    *(bf16x4*)(wb + idx) = hv;
  } else if (i < 557056) {              // R2: pads
    int idx = i - 524288;
    float4 z = {0.f, 0.f, 0.f, 0.f};
    if (idx < 16384) {        // pKb: 2b x 128 pad-rows x 512 cols
      int b = idx >> 13, r = (idx & 8191) >> 6, c = idx & 63;
      int row = (r < 64) ? r : (S_LEN + r);
      *(float4*)(pKb + ((size_t)b * SP + row) * 512 + c * 8) = z;
    } else {                  // pVT: 2b x 512 rows x 128 pad-cols
      int j = idx - 16384;
      int b = j >> 13, h = (j & 8191) >> 4, v = j & 15;
      int col = (v < 8) ? v * 8 : (S_LEN + PAD + (v - 8) * 8);
      *(float4*)(pVT + ((size_t)b * 512 + h) * SP + col) = z;
    }
  } else {                              // R3: rope tables
    int idx = i - 557056;               // [0, 262144) = s*128 + jj
    int s = idx >> 7, jj = idx & 127;
    float fqA = exp2f(-(float)jj * 0.10381025296523f);          // i = 2jj
    float fqB = exp2f(-(float)(2 * jj + 1) * 0.05190512648262f); // i = 2jj+1
    float aA = (float)s * fqA;
    float aB = (float)s * fqB;
    sinT[s * 256 + jj]       = sinf(aA);
    sinT[s * 256 + jj + 128] = cosf(aA);
    cosT[s * 256 + jj]       = sinf(aB);
    cosT[s * 256 + jj + 128] = cosf(aB);
  }
}

// ---------------- 1-pass bf16 MFMA GEMM, BK=64 (round-10 verified) ------
// MFR=2 for QKV: grid (64,12)=768 blocks, 48KB LDS -> 3 blocks/CU EXACTLY
// (vs MFR=4: 384 blocks at 2/CU capacity = 1.5/CU uneven, ~25% imbalance).
template<int MFR, int MODE>
__global__ __launch_bounds__(256) void gemm_k(
    const bf16* __restrict__ Ab, const bf16* __restrict__ Wb,
    const float* __restrict__ bq, const float* __restrict__ bk,
    const float* __restrict__ bv,
    const float* __restrict__ sinT, const float* __restrict__ cosT,
    bf16* __restrict__ oQ, bf16* __restrict__ oK, bf16* __restrict__ oVT,
    float* __restrict__ oOut)
{
  constexpr int BM = MFR * 32;
  constexpr int ABYTES = BM * 128;
  constexpr int BUFB = ABYTES + 128 * 128;
  __shared__ __align__(16) unsigned char smem[2 * BUFB];
  const int tid = threadIdx.x;
  const int lane = tid & 63, wid = tid >> 6;
  const int wm = wid >> 1, wn = wid & 1;
  const int row0 = blockIdx.x * BM;
  const int wrow0 = (MODE == 0 ? 0 : 1536) + blockIdx.y * 128;
  const int lr = lane & 15, lk = lane >> 4;

  f32x4 acc[MFR][4] = {};

  auto stage = [&](int k0, int bufsel) {
    unsigned char* buf = smem + bufsel * BUFB;
#pragma unroll
    for (int i = 0; i < MFR; i++) {         // A: BM rows x 8 slots of 16B
      int c = tid + i * 256;
      int r = c >> 3, p = c & 7, l = p ^ (r & 7);
      GLDS16(Ab + (size_t)(row0 + r) * 512 + k0 + l * 8, buf + c * 16);
    }
#pragma unroll
    for (int j = 0; j < 4; j++) {           // B: 128 rows x 8 slots of 16B
      int c = tid + j * 256;
      int r = c >> 3, p = c & 7, l = p ^ (r & 7);
      GLDS16(Wb + (size_t)(wrow0 + r) * 512 + k0 + l * 8, buf + ABYTES + c * 16);
    }
  };

  stage(0, 0);
  __syncthreads();
  for (int t = 0; t < 8; t++) {
    if (t < 7) stage((t + 1) * 64, (t + 1) & 1);
    const unsigned char* buf = smem + (t & 1) * BUFB;
    bf16x8 bfr[4][2];
#pragma unroll
    for (int ni = 0; ni < 4; ni++) {
      int r = wn * 64 + ni * 16 + lr;
      const unsigned char* base = buf + ABYTES + r * 128;
      int sw = (r & 7) << 4;
      bfr[ni][0] = *(const bf16x8*)(base + ((lk * 16) ^ sw));
      bfr[ni][1] = *(const bf16x8*)(base + ((64 + lk * 16) ^ sw));
    }
#pragma unroll
    for (int mi = 0; mi < MFR; mi++) {
      int r = wm * (MFR * 16) + mi * 16 + lr;
      const unsigned char* base = buf + r * 128;
      int sw = (r & 7) << 4;
      bf16x8 a0 = *(const bf16x8*)(base + ((lk * 16) ^ sw));
      bf16x8 a1 = *(const bf16x8*)(base + ((64 + lk * 16) ^ sw));
#pragma unroll
      for (int ni = 0; ni < 4; ni++) {
        acc[mi][ni] = __builtin_amdgcn_mfma_f32_16x16x32_bf16(a0, bfr[ni][0], acc[mi][ni], 0, 0, 0);
        acc[mi][ni] = __builtin_amdgcn_mfma_f32_16x16x32_bf16(a1, bfr[ni][1], acc[mi][ni], 0, 0, 0);
      }
    }
    __syncthreads();
  }

  const int rowb = row0 + wm * (MFR * 16) + ((lane >> 4) * 4);
  if (MODE == 1) {
#pragma unroll
    for (int mi = 0; mi < MFR; mi++)
#pragma unroll
      for (int ni = 0; ni < 4; ni++) {
        int col = blockIdx.y * 128 + wn * 64 + ni * 16 + (lane & 15);
        float bb = bq[col];
#pragma unroll
        for (int g = 0; g < 4; g++) {
          int rr = rowb + mi * 16 + g;
          oOut[(size_t)rr * 512 + col] = acc[mi][ni][g] + bb;
        }
      }
    return;
  }
  const int region = blockIdx.y >> 2;                 // 0=Q 1=K 2=V
  const float* bias = (region == 0) ? bq : (region == 1) ? bk : bv;
  const int cm0 = (blockIdx.y & 3) * 128;
#pragma unroll
  for (int mi = 0; mi < MFR; mi++)
#pragma unroll
    for (int ni = 0; ni < 4; ni++) {
      int c = cm0 + wn * 64 + ni * 16 + (lane & 15);
      float bb = bias[c];
      if (region == 2) {
#pragma unroll
        for (int g = 0; g < 4; g++) {
          int rr = rowb + mi * 16 + g;
          int b = rr >> 11, s = rr & 2047;
          oVT[((size_t)b * 512 + c) * SP + PAD + s] = (bf16)(acc[mi][ni][g] + bb);
        }
      } else {
        int j = c >> 1, par = c & 1;
#pragma unroll
        for (int g = 0; g < 4; g++) {
          int rr = rowb + mi * 16 + g;
          int s = rr & 2047;
          float v = acc[mi][ni][g] + bb;
          float p = __shfl_xor(v, 1);
          float es = sinT[s * 256 + j], ec = cosT[s * 256 + j];
          float res = par ? (p * es + v * ec) : (v * ec - p * es);
          int oc = par ? (j + 256) : j;
          if (region == 0) oQ[(size_t)rr * 512 + oc] = (bf16)res;
          else { int b = rr >> 11; oK[((size_t)b * SP + PAD + s) * 512 + oc] = (bf16)res; }
        }
      }
    }
}

// ---------------- banded MFMA attention, 512 threads, K-split -----------
// (round-13 verified)
__global__ __launch_bounds__(512) void attn_mfma_k(
    const bf16* __restrict__ rQb, const bf16* __restrict__ pKb,
    const bf16* __restrict__ pVT, bf16* __restrict__ ab)
{
  __shared__ __align__(16) unsigned char smem[98304];
  const int tid = threadIdx.x, lane = tid & 63, w = tid >> 6;
  const int g = w >> 2, ww = w & 3, gtid = tid & 255;
  const int q0g = blockIdx.x * TQ;
  const int nbase = blockIdx.y * 256;
  const int b = q0g >> 11, s0 = q0g & 2047;
  const int lr = lane & 15, lk = lane >> 4;
  const int GB = g * 49152;
  const int OFF_P = 43008;

  // ---- phase 1: partial scores, K-split across wave groups
  f32x4 sacc[5] = {};
  const int tm = ww >> 1, tnb = (ww & 1) * 5;

  auto stageQK = [&](int k0, int sel) {
    {   // Q: 32 rows x 8 slots (128B/row), linear dest per wave
      int r = gtid >> 3, p = gtid & 7, l = p ^ (r & 7);
      GLDS16(rQb + (size_t)(q0g + r) * 512 + k0 + l * 8,
             smem + GB + sel * 4096 + gtid * 16);
    }
#pragma unroll
    for (int i = 0; i < 5; i++) {  // K: 160 rows x 8 slots
      int c = gtid + i * 256;
      int r = c >> 3, p = c & 7, l = p ^ (r & 7);
      GLDS16(pKb + ((size_t)b * SP + s0 + r) * 512 + k0 + l * 8,
             smem + GB + 8192 + sel * 20480 + c * 16);
    }
  };

  stageQK(g * 256, 0);
  __syncthreads();
  for (int t = 0; t < 4; t++) {
    if (t < 3) stageQK(g * 256 + (t + 1) * 64, (t + 1) & 1);
    const unsigned char* qb = smem + GB + (t & 1) * 4096;
    const unsigned char* kb = smem + GB + 8192 + (t & 1) * 20480;
    __builtin_amdgcn_s_setprio(1);
#pragma unroll
    for (int kk = 0; kk < 2; kk++) {
      int arow = tm * 16 + lr;
      bf16x8 a = *(const bf16x8*)(qb + arow * 128 + (((kk * 64 + lk * 16) ^ ((arow & 7) << 4))));
#pragma unroll
      for (int i = 0; i < 5; i++) {
        int brow = (tnb + i) * 16 + lr;
        bf16x8 bb = *(const bf16x8*)(kb + brow * 128 + (((kk * 64 + lk * 16) ^ ((brow & 7) << 4))));
        sacc[i] = __builtin_amdgcn_mfma_f32_16x16x32_bf16(a, bb, sacc[i], 0, 0, 0);
      }
    }
    __builtin_amdgcn_s_setprio(0);
    __syncthreads();
  }
  {   // write raw partial scores f32 [32][164] at group offset
    float* sc = (float*)(smem + g * 21504);
#pragma unroll
    for (int i = 0; i < 5; i++) {
      int col = (tnb + i) * 16 + lr;
#pragma unroll
      for (int gg = 0; gg < 4; gg++) {
        int row = tm * 16 + lk * 4 + gg;
        sc[row * 164 + col] = sacc[i][gg];
      }
    }
  }
  __syncthreads();
  // ---- phase 2: banded softmax, 16 threads per row (512 threads)
  {
    const float* sA = (const float*)smem;
    const float* sB = (const float*)(smem + 21504);
    bf16* P = (bf16*)(smem + OFF_P);
    int row = tid >> 4, j0 = tid & 15;
    float vals[10];
    float mx = -1e30f;
#pragma unroll
    for (int i = 0; i < 10; i++) {
      int j = j0 + i * 16;
      bool valid = (j >= row) && (j <= row + 127);
      float v = valid ? (sA[row * 164 + j] + sB[row * 164 + j]) * SCALE : -1e30f;
      vals[i] = v;
      mx = fmaxf(mx, v);
    }
#pragma unroll
    for (int off = 1; off < 16; off <<= 1) mx = fmaxf(mx, __shfl_xor(mx, off));
    float sum = 0.f;
#pragma unroll
    for (int i = 0; i < 10; i++) {
      float e = (vals[i] > -1e29f) ? __expf(vals[i] - mx) : 0.f;
      vals[i] = e; sum += e;
    }
#pragma unroll
    for (int off = 1; off < 16; off <<= 1) sum += __shfl_xor(sum, off);
    float inv = 1.f / sum;
#pragma unroll
    for (int i = 0; i < 10; i++)
      P[row * 168 + j0 + i * 16] = (bf16)(vals[i] * inv);   // stride 336B
  }
  // ---- phase 3: out = P @ V, 2 chunks of 128 h-rows, 8 waves
  const bf16* pVTb = pVT + (size_t)b * 512 * SP;
  const int utm = w >> 2, utnb = (w & 3) * 2;
  for (int n0 = nbase; n0 < nbase + 256; n0 += 128) {
    __syncthreads();
    {   // stage V chunk: 128 h-rows x 160 keys, LDS row stride 336B
      int r = tid >> 2, q = tid & 3;
      const bf16* src = pVTb + (size_t)(n0 + r) * SP + s0;
#pragma unroll
      for (int i = 0; i < 5; i++) {
        int slot = q * 5 + i;
        float4 v = *(const float4*)(src + slot * 8);
        *(float4*)(smem + r * 336 + slot * 16) = v;
      }
    }
    __syncthreads();
    f32x4 oacc[2] = {};
    __builtin_amdgcn_s_setprio(1);
#pragma unroll
    for (int tk = 0; tk < 5; tk++) {
      bf16x8 a = *(const bf16x8*)(smem + OFF_P + (utm * 16 + lr) * 336 + tk * 64 + lk * 16);
#pragma unroll
      for (int i = 0; i < 2; i++) {
        int brow = (utnb + i) * 16 + lr;
        bf16x8 bb = *(const bf16x8*)(smem + brow * 336 + tk * 64 + lk * 16);
        oacc[i] = __builtin_amdgcn_mfma_f32_16x16x32_bf16(a, bb, oacc[i], 0, 0, 0);
      }
    }
    __builtin_amdgcn_s_setprio(0);
#pragma unroll
    for (int i = 0; i < 2; i++) {
      int col = n0 + (utnb + i) * 16 + lr;
#pragma unroll
      for (int gg = 0; gg < 4; gg++) {
        int row = utm * 16 + lk * 4 + gg;
        ab[(size_t)(q0g + row) * 512 + col] = (bf16)oacc[i][gg];
      }
    }
  }
}

// ---------------- launch -------------------------------------------------
extern "C" void kernel_launch(void* const* d_in, const int* in_sizes, int n_in,
                              void* d_out, int out_size, void* d_ws, size_t ws_size,
                              hipStream_t stream) {
  const float* x  = (const float*)d_in[0];
  const float* Wq = (const float*)d_in[1];
  const float* bq = (const float*)d_in[2];
  const float* Wk = (const float*)d_in[3];
  const float* bk = (const float*)d_in[4];
  const float* Wv = (const float*)d_in[5];
  const float* bv = (const float*)d_in[6];
  const float* Wo = (const float*)d_in[7];
  const float* bo = (const float*)d_in[8];
  float* out = (float*)d_out;

  const size_t NQ = (size_t)B_SZ * S_LEN * H_DIM;  // 2,097,152
  const size_t NP = (size_t)B_SZ * SP * H_DIM;     // 2,228,224
  float* sinT = (float*)d_ws;                      // 524288 f32
  float* cosT = sinT + (size_t)S_LEN * 256;        // 524288 f32
  bf16* xb  = (bf16*)(cosT + (size_t)S_LEN * 256); // NQ
  bf16* wb  = xb + NQ;                             // 2048*512
  bf16* rQb = wb + 2048 * 512;                     // NQ
  bf16* pKb = rQb + NQ;                            // NP
  bf16* pVT = pKb + NP;                            // NP
  bf16* ab  = pVT + NP;                            // NQ

  prep_k<<<3200, 256, 0, stream>>>(x, Wq, Wk, Wv, Wo, xb, wb,
                                   pKb, pVT, sinT, cosT);

  // MFR=2: 768 blocks, 3/CU exact (was MFR=4: 384 blocks, 1.5/CU uneven)
  gemm_k<2, 0><<<dim3(64, 12), 256, 0, stream>>>(xb, wb,
      bq, bk, bv, sinT, cosT, rQb, pKb, pVT, nullptr);

  attn_mfma_k<<<dim3(B_SZ * S_LEN / TQ, 2), 512, 0, stream>>>(rQb, pKb, pVT, ab);

  gemm_k<2, 1><<<dim3(64, 4), 256, 0, stream>>>(ab, wb,
      bo, nullptr, nullptr, sinT, cosT, nullptr, nullptr, nullptr, out);
}